// Round 14
// baseline (1056.016 us; speedup 1.0000x reference)
//
#include <hip/hip_runtime.h>

typedef unsigned short u16;
typedef float f32x4 __attribute__((ext_vector_type(4)));
typedef short s16x8 __attribute__((ext_vector_type(8)));
typedef unsigned short u16x4 __attribute__((ext_vector_type(4)));
typedef unsigned short u16x8 __attribute__((ext_vector_type(8)));

__device__ __forceinline__ u16 f2b(float x){
  union{float f; unsigned u;} a; a.f=x;
  return (u16)((a.u + 0x7fffu + ((a.u>>16)&1u))>>16);
}
__device__ __forceinline__ float b2f(u16 x){
  union{unsigned u; float f;} a; a.u = ((unsigned)x)<<16; return a.f;
}

// Async global->LDS, 16B per lane. Dest wave-uniform base; HW adds lane*16.
__device__ __forceinline__ void gload16(const u16* g, u16* l){
  __builtin_amdgcn_global_load_lds(
      (const __attribute__((address_space(1))) void*)g,
      (__attribute__((address_space(3))) void*)l, 16, 0, 0);
}

__device__ __forceinline__ float block_reduce(float v, int op, float* sh){
  #pragma unroll
  for (int o=32;o>0;o>>=1){
    float t = __shfl_down(v, o);
    v = op ? fmaxf(v,t) : v+t;
  }
  int w = threadIdx.x>>6;
  if ((threadIdx.x&63)==0) sh[w]=v;
  __syncthreads();
  float r = op ? fmaxf(fmaxf(sh[0],sh[1]),fmaxf(sh[2],sh[3]))
               : (sh[0]+sh[1]+sh[2]+sh[3]);
  __syncthreads();
  return r;
}

// ---------------------------------------------------------------------------
// NT GEMM: C[m][n] = sum_k A[m][k] * B[n][k]  (+bias[n]). Optional row gather
// on B. Tile = (MT*32) x 128, BK=64, 256 thr. global_load_lds staging, linear
// LDS, both-sides XOR swizzle. MFMA computes C^T -> 4 consecutive n per lane.
// MT ladder (measured rounds 8-12, 2-barrier structure): occupancy dominates
// instruction mix until >=4 blocks/CU. MT=1: 32-tile (4/CU for N=1024 fleet).
// MT=2: 64-tile. MT=4: 128-tile (sweet spot at >=4/CU). MT=8: regressed
// (11% occupancy, round 12) — do not use without a deep-pipelined schedule.
// SWAP=1 (x indexes n-tile): only when B-panel reuse dominates (gather-scores).
// EPI: 0 bf16+bias, 1 sqrelu bf16+bias, 2 f32 residual += (+bias),
//      3 f32 store, 5 bf16 store * (1/32) (cross scores), 6 bf16 store plain
// ---------------------------------------------------------------------------
template<int EPI, bool BG, int MT, int SWAP>
__global__ __launch_bounds__(256)
void gemm_nt(const u16* __restrict__ A,
             long a_s1, long a_s2, int azd, int lda,
             const u16* __restrict__ B, const int* __restrict__ bidx,
             int bidx_zs, long b_s1, long b_s2, int bzd, int ldb,
             const float* __restrict__ bias, int bias_zs,
             void* __restrict__ Cv, long c_s1, long c_s2, int czd, int ldc,
             int K)
{
  __shared__ u16 lA[MT*32*64];
  __shared__ u16 lB[128*64];
  const int tid = threadIdx.x;
  const int z = blockIdx.z;
  const int m0 = (SWAP ? blockIdx.y : blockIdx.x) * (MT*32);
  const int n0 = (SWAP ? blockIdx.x : blockIdx.y) * 128;
  const u16* Ab = A + (long)(z/azd)*a_s1 + (long)(z%azd)*a_s2;
  const u16* Bb = B + (long)(z/bzd)*b_s1 + (long)(z%bzd)*b_s2;
  const int* bi = BG ? (bidx + (long)z*bidx_zs) : nullptr;

  const int w = tid >> 6, lane = tid & 63;
  const int wr = w >> 1, wc = w & 1;
  const int lm = lane >> 4, ln = lane & 15;

  f32x4 acc[MT][4];
  #pragma unroll
  for (int i=0;i<MT;i++)
    #pragma unroll
    for (int j=0;j<4;j++) acc[i][j] = (f32x4){0.f,0.f,0.f,0.f};

  for (int kt = 0; kt < K; kt += 64) {
    __syncthreads();
    #pragma unroll
    for (int i = 0; i < MT; i++) {
      int c = i*256 + tid;
      int r = c >> 3;
      int kc = ((c & 7) ^ (r & 7)) << 3;       // inverse-swizzled source chunk
      gload16(Ab + (long)(m0+r)*lda + kt + kc, &lA[(i*256 + (tid & 192))*8]);
    }
    #pragma unroll
    for (int i = 0; i < 4; i++) {
      int c = i*256 + tid;
      int r = c >> 3;
      int kc = ((c & 7) ^ (r & 7)) << 3;
      long brow = BG ? (long)bi[n0 + r] : (long)(n0 + r);
      gload16(Bb + brow*(long)ldb + kt + kc, &lB[(i*256 + (tid & 192))*8]);
    }
    __syncthreads();
    #pragma unroll
    for (int kk = 0; kk < 2; kk++) {
      const int chunk = kk*4 + lm;
      const int ksw = ((chunk ^ (ln & 7)) << 3);
      s16x8 af[MT], bf[4];
      #pragma unroll
      for (int i=0;i<MT;i++) af[i] = *(const s16x8*)(&lA[(wr*(MT*16) + i*16 + ln)*64 + ksw]);
      #pragma unroll
      for (int j=0;j<4;j++) bf[j] = *(const s16x8*)(&lB[(wc*64 + j*16 + ln)*64 + ksw]);
      #pragma unroll
      for (int i=0;i<MT;i++)
        #pragma unroll
        for (int j=0;j<4;j++)   // swapped operands -> C^T fragment layout
          acc[i][j] = __builtin_amdgcn_mfma_f32_16x16x32_bf16(bf[j], af[i], acc[i][j], 0,0,0);
    }
  }

  const long co = (long)(z/czd)*c_s1 + (long)(z%czd)*c_s2;
  const float* biasp = (EPI==3 || EPI==5 || EPI==6) ? nullptr : (bias + (long)z*bias_zs);
  #pragma unroll
  for (int i=0;i<MT;i++) {
    const int m = m0 + wr*(MT*16) + i*16 + ln;     // col of C^T = m
    #pragma unroll
    for (int j=0;j<4;j++) {
      const int nb = n0 + wc*64 + j*16 + lm*4;     // row of C^T = n (4 consec)
      f32x4 v = acc[i][j];
      if constexpr (EPI == 3) {
        *(f32x4*)((float*)Cv + co + (long)m*ldc + nb) = v;
      } else if constexpr (EPI == 5) {
        u16x4 pk;
        pk[0]=f2b(v[0]*0.03125f); pk[1]=f2b(v[1]*0.03125f);
        pk[2]=f2b(v[2]*0.03125f); pk[3]=f2b(v[3]*0.03125f);
        *(u16x4*)((u16*)Cv + co + (long)m*ldc + nb) = pk;
      } else if constexpr (EPI == 6) {
        u16x4 pk;
        pk[0]=f2b(v[0]); pk[1]=f2b(v[1]); pk[2]=f2b(v[2]); pk[3]=f2b(v[3]);
        *(u16x4*)((u16*)Cv + co + (long)m*ldc + nb) = pk;
      } else {
        float4 vb = *(const float4*)(biasp + nb);
        if constexpr (EPI == 2) {
          float* Cf = (float*)Cv + co + (long)m*ldc + nb;
          f32x4 old = *(f32x4*)Cf;
          old[0] += v[0]+vb.x; old[1] += v[1]+vb.y;
          old[2] += v[2]+vb.z; old[3] += v[3]+vb.w;
          *(f32x4*)Cf = old;
        } else {
          float x0 = v[0]+vb.x, x1 = v[1]+vb.y, x2 = v[2]+vb.z, x3 = v[3]+vb.w;
          if constexpr (EPI == 1) {
            x0 = x0>0.f ? x0*x0 : 0.f; x1 = x1>0.f ? x1*x1 : 0.f;
            x2 = x2>0.f ? x2*x2 : 0.f; x3 = x3>0.f ? x3*x3 : 0.f;
          }
          u16x4 pk; pk[0]=f2b(x0); pk[1]=f2b(x1); pk[2]=f2b(x2); pk[3]=f2b(x3);
          *(u16x4*)((u16*)Cv + co + (long)m*ldc + nb) = pk;
        }
      }
    }
  }
}

// ---------------------------------------------------------------------------
// Fused QKV projection, 64x128 tiles. Grid (64,24): x = m-tile (A-co-locate).
// ---------------------------------------------------------------------------
__global__ __launch_bounds__(256)
void gemm_qkv(const u16* __restrict__ A, const u16* __restrict__ Bw,
              const float* __restrict__ bias,
              u16* __restrict__ Qs, u16* __restrict__ Ks, u16* __restrict__ VsT)
{
  __shared__ u16 lA[64*64];
  __shared__ u16 lB[128*64];
  const int tid = threadIdx.x;
  const int m0 = blockIdx.x * 64;
  const int n0 = blockIdx.y * 128;
  const int w = tid >> 6, lane = tid & 63;
  const int wr = w >> 1, wc = w & 1;
  const int lm = lane >> 4, ln = lane & 15;
  const bool tp = (n0 < 2048);

  f32x4 acc[2][4];
  #pragma unroll
  for (int i=0;i<2;i++)
    #pragma unroll
    for (int j=0;j<4;j++) acc[i][j] = (f32x4){0.f,0.f,0.f,0.f};

  for (int kt = 0; kt < 1024; kt += 64) {
    __syncthreads();
    #pragma unroll
    for (int i = 0; i < 2; i++) {
      int c = i*256 + tid;
      int r = c >> 3;
      int kc = ((c & 7) ^ (r & 7)) << 3;
      gload16(A + (long)(m0+r)*1024 + kt + kc, &lA[(i*256 + (tid & 192))*8]);
    }
    #pragma unroll
    for (int i = 0; i < 4; i++) {
      int c = i*256 + tid;
      int r = c >> 3;
      int kc = ((c & 7) ^ (r & 7)) << 3;
      gload16(Bw + (long)(n0+r)*1024 + kt + kc, &lB[(i*256 + (tid & 192))*8]);
    }
    __syncthreads();
    #pragma unroll
    for (int kk = 0; kk < 2; kk++) {
      const int chunk = kk*4 + lm;
      const int ksw = ((chunk ^ (ln & 7)) << 3);
      s16x8 af[2], bf[4];
      #pragma unroll
      for (int i=0;i<2;i++) af[i] = *(const s16x8*)(&lA[(wr*32 + i*16 + ln)*64 + ksw]);
      #pragma unroll
      for (int j=0;j<4;j++) bf[j] = *(const s16x8*)(&lB[(wc*64 + j*16 + ln)*64 + ksw]);
      if (tp) {
        #pragma unroll
        for (int i=0;i<2;i++)
          #pragma unroll
          for (int j=0;j<4;j++)
            acc[i][j] = __builtin_amdgcn_mfma_f32_16x16x32_bf16(bf[j], af[i], acc[i][j], 0,0,0);
      } else {
        #pragma unroll
        for (int i=0;i<2;i++)
          #pragma unroll
          for (int j=0;j<4;j++)
            acc[i][j] = __builtin_amdgcn_mfma_f32_16x16x32_bf16(af[i], bf[j], acc[i][j], 0,0,0);
      }
    }
  }

  if (tp) {
    u16* dst = (n0 < 1024) ? Qs : Ks;
    #pragma unroll
    for (int i=0;i<2;i++) {
      const int m = m0 + wr*32 + i*16 + ln;
      #pragma unroll
      for (int j=0;j<4;j++) {
        const int gn = n0 + wc*64 + j*16 + lm*4;
        float4 vb = *(const float4*)(bias + gn);
        f32x4 v = acc[i][j];
        u16x4 pk;
        pk[0]=f2b(v[0]+vb.x); pk[1]=f2b(v[1]+vb.y);
        pk[2]=f2b(v[2]+vb.z); pk[3]=f2b(v[3]+vb.w);
        *(u16x4*)(dst + (long)m*1024 + (gn & 1023)) = pk;
      }
    }
  } else {
    #pragma unroll
    for (int i=0;i<2;i++) {
      const int gmb = m0 + wr*32 + i*16 + lm*4;
      #pragma unroll
      for (int j=0;j<4;j++) {
        const int gn = n0 + wc*64 + j*16 + ln;
        const float bb = bias[gn];
        f32x4 v = acc[i][j];
        long addr = (long)(gmb >> 10)*1048576 + (long)(gn - 2048)*1024 + (gmb & 1023);
        u16x4 pk;
        #pragma unroll
        for (int r=0;r<4;r++) pk[r] = f2b(v[r] + bb);
        *(u16x4*)(VsT + addr) = pk;
      }
    }
  }
}

// ---------------------------------------------------------------------------
// Flash self-attention: causal, H=8, d=128. T14 reg-prefetch + T5 setprio +
// T13 defer-max.
// ---------------------------------------------------------------------------
__global__ __launch_bounds__(256)
void flash_self(const u16* __restrict__ Qs, const u16* __restrict__ Ks,
                const u16* __restrict__ VsT, u16* __restrict__ O)
{
  __shared__ u16 lK[64][128];
  __shared__ u16 lV[128][64];
  __shared__ u16 lP[4][16][64];

  const int tid = threadIdx.x;
  const int w = tid >> 6, lane = tid & 63;
  const int g = lane >> 4, ln = lane & 15;
  const int bh = blockIdx.x;
  const int b = bh >> 3, h = bh & 7;
  const int y = blockIdx.y;
  const int qt = (y < 8) ? (15 - y) : (y - 8);

  const long qrow0 = (long)b*1024 + qt*64 + w*16;
  const u16* Qp = Qs + qrow0*1024 + h*128;
  const u16* Kp = Ks + (long)b*1048576 + h*128;
  const u16* Vp = VsT + (long)b*1048576 + (long)h*131072;

  s16x8 bq[4];
  #pragma unroll
  for (int ks=0;ks<4;ks++)
    bq[ks] = *(const s16x8*)(Qp + (long)ln*1024 + ks*32 + g*8);

  f32x4 ao[8];
  #pragma unroll
  for (int i=0;i<8;i++) ao[i] = (f32x4){0.f,0.f,0.f,0.f};
  float mrun = -3.0e38f, lrun = 0.f;
  const int qc = qt*64 + w*16 + ln;

  const int nt = qt + 1;

  s16x8 pK[4], pV[4];
  #pragma unroll
  for (int i=0;i<4;i++){
    int c = i*256 + tid;
    int rr = c >> 4, d8 = c & 15;
    pK[i] = *(const s16x8*)(Kp + (long)rr*1024 + d8*8);
    int dd = c >> 3, k8 = c & 7;
    pV[i] = *(const s16x8*)(Vp + (long)dd*1024 + k8*8);
  }

  for (int kt = 0; kt < nt; ++kt) {
    __syncthreads();
    #pragma unroll
    for (int i=0;i<4;i++){
      int c = i*256 + tid;
      int rr = c >> 4, d8 = c & 15;
      *(s16x8*)(&lK[rr][(d8 ^ (rr&7))*8]) = pK[i];
      int dd = c >> 3, k8 = c & 7;
      *(s16x8*)(&lV[dd][(k8 ^ (dd&7))*8]) = pV[i];
    }
    __syncthreads();
    if (kt+1 < nt){
      const u16* src  = Kp + (long)((kt+1)*64)*1024;
      const u16* vsrc = Vp + (kt+1)*64;
      #pragma unroll
      for (int i=0;i<4;i++){
        int c = i*256 + tid;
        int rr = c >> 4, d8 = c & 15;
        pK[i] = *(const s16x8*)(src + (long)rr*1024 + d8*8);
        int dd = c >> 3, k8 = c & 7;
        pV[i] = *(const s16x8*)(vsrc + (long)dd*1024 + k8*8);
      }
    }

    f32x4 as_[4];
    #pragma unroll
    for (int i=0;i<4;i++) as_[i] = (f32x4){0.f,0.f,0.f,0.f};
    __builtin_amdgcn_s_setprio(1);
    #pragma unroll
    for (int ks=0;ks<4;ks++){
      #pragma unroll
      for (int mi=0;mi<4;mi++){
        s16x8 ak = *(const s16x8*)(&lK[16*mi + ln][((g + 4*ks) ^ (ln&7))*8]);
        as_[mi] = __builtin_amdgcn_mfma_f32_16x16x32_bf16(ak, bq[ks], as_[mi], 0,0,0);
      }
    }
    __builtin_amdgcn_s_setprio(0);

    const int kkb = kt*64 + 4*g;
    float mx = -3.0e38f;
    #pragma unroll
    for (int mi=0;mi<4;mi++)
      #pragma unroll
      for (int r=0;r<4;r++){
        float s = as_[mi][r] * 0.08838834764831845f;
        if (kkb + 16*mi + r > qc) s = -3.0e38f;
        as_[mi][r] = s;
        mx = fmaxf(mx, s);
      }
    mx = fmaxf(mx, __shfl_xor(mx, 16));
    mx = fmaxf(mx, __shfl_xor(mx, 32));
    if (!__all(mx - mrun <= 8.0f)) {
      float mnew = fmaxf(mrun, mx);
      float alpha = __expf(mrun - mnew);
      lrun *= alpha;
      #pragma unroll
      for (int mi=0;mi<8;mi++)
        #pragma unroll
        for (int r=0;r<4;r++)
          ao[mi][r] *= alpha;
      mrun = mnew;
    }
    float sum = 0.f;
    #pragma unroll
    for (int mi=0;mi<4;mi++){
      u16x4 pk;
      #pragma unroll
      for (int r=0;r<4;r++){
        float p = __expf(as_[mi][r] - mrun);
        sum += p;
        pk[r] = f2b(p);
      }
      *(u16x4*)(&lP[w][ln][(((2*mi + (g>>1)) ^ (ln&7))<<3) + (g&1)*4]) = pk;
    }
    sum += __shfl_xor(sum, 16);
    sum += __shfl_xor(sum, 32);
    lrun += sum;

    __builtin_amdgcn_s_setprio(1);
    #pragma unroll
    for (int ks=0;ks<2;ks++){
      s16x8 bp = *(const s16x8*)(&lP[w][ln][((4*ks + g) ^ (ln&7))*8]);
      #pragma unroll
      for (int mi=0;mi<8;mi++){
        s16x8 av = *(const s16x8*)(&lV[16*mi + ln][((g + 4*ks) ^ (ln&7))*8]);
        ao[mi] = __builtin_amdgcn_mfma_f32_16x16x32_bf16(av, bp, ao[mi], 0,0,0);
      }
    }
    __builtin_amdgcn_s_setprio(0);
  }

  const float inv = 1.f/lrun;
  #pragma unroll
  for (int mi=0;mi<8;mi++){
    u16x4 pk;
    #pragma unroll
    for (int r=0;r<4;r++) pk[r] = f2b(ao[mi][r]*inv);
    *(u16x4*)(O + (qrow0 + ln)*1024 + h*128 + 16*mi + 4*g) = pk;
  }
}

// ---------------------------------------------------------------------------
// Gather-transpose: VT[d][s] = Vtab[idx[s]][d].
// ---------------------------------------------------------------------------
__global__ __launch_bounds__(256)
void gather_T(const u16* __restrict__ Vtab, const int* __restrict__ idx,
              u16* __restrict__ VT)
{
  __shared__ u16 t[64][72];
  const int s0 = blockIdx.x*64, d0 = blockIdx.y*64;
  const int tr = threadIdx.x>>3, tc = threadIdx.x&7;
  #pragma unroll
  for (int i=0;i<2;i++){
    int s = tr + i*32;
    long row = idx[s0+s];
    *(s16x8*)(&t[s][tc*8]) = *(const s16x8*)(Vtab + row*1024 + d0 + tc*8);
  }
  __syncthreads();
  #pragma unroll
  for (int i=0;i<2;i++){
    int d = tr + i*32;
    u16 out[8];
    #pragma unroll
    for (int j=0;j<8;j++) out[j] = t[tc*8+j][d];
    *(s16x8*)(VT + (long)(d0+d)*8192 + s0 + tc*8) = *(s16x8*)out;
  }
}

// ---------------------------------------------------------------------------
// Sum 8 bf16 split-K partial planes (1M elems each) -> bf16.
// ---------------------------------------------------------------------------
__global__ __launch_bounds__(256)
void reduce8b(const u16* __restrict__ Pp, u16* __restrict__ Ob){
  long i = ((long)blockIdx.x*256 + threadIdx.x)*4;
  float s0=0.f, s1=0.f, s2=0.f, s3=0.f;
  #pragma unroll
  for (int p=0;p<8;p++){
    u16x4 t = *(const u16x4*)(Pp + (long)p*1048576 + i);
    s0 += b2f(t[0]); s1 += b2f(t[1]); s2 += b2f(t[2]); s3 += b2f(t[3]);
  }
  u16x4 pk; pk[0]=f2b(s0); pk[1]=f2b(s1); pk[2]=f2b(s2); pk[3]=f2b(s3);
  *(u16x4*)(Ob + i) = pk;
}

// ---------------------------------------------------------------------------
template<int TWO>
__global__ __launch_bounds__(256)
void ln_kernel(const float* __restrict__ X,
               const float* __restrict__ g1, const float* __restrict__ bb1,
               const float* __restrict__ g2, const float* __restrict__ bb2,
               u16* __restrict__ o1, u16* __restrict__ o2)
{
  __shared__ float sh[4];
  const long row = blockIdx.x;
  const int tid = threadIdx.x;
  const float* x = X + row*1024;
  float4 t = *(const float4*)(x + tid*4);
  float s = t.x+t.y+t.z+t.w;
  float m = block_reduce(s, 0, sh) * (1.f/1024.f);
  float d0=t.x-m, d1=t.y-m, d2=t.z-m, d3=t.w-m;
  float s2 = d0*d0+d1*d1+d2*d2+d3*d3;
  float var = block_reduce(s2, 0, sh) * (1.f/1024.f);
  float r = rsqrtf(var + 1e-5f);
  const int c = tid*4;
  {
    float4 g = *(const float4*)(g1+c);
    float4 b = *(const float4*)(bb1+c);
    u16x4 pk;
    pk[0]=f2b(d0*r*g.x+b.x); pk[1]=f2b(d1*r*g.y+b.y);
    pk[2]=f2b(d2*r*g.z+b.z); pk[3]=f2b(d3*r*g.w+b.w);
    *(u16x4*)(o1 + row*1024 + c) = pk;
  }
  if constexpr (TWO) {
    float4 g = *(const float4*)(g2+c);
    float4 b = *(const float4*)(bb2+c);
    u16x4 pk;
    pk[0]=f2b(d0*r*g.x+b.x); pk[1]=f2b(d1*r*g.y+b.y);
    pk[2]=f2b(d2*r*g.z+b.z); pk[3]=f2b(d3*r*g.w+b.w);
    *(u16x4*)(o2 + row*1024 + c) = pk;
  }
}

// ---------------------------------------------------------------------------
// Fused z-init + LN(c_lnq): z[row] = emb[idx]; zn[row] = LN(z[row]).
// ---------------------------------------------------------------------------
__global__ __launch_bounds__(256)
void zinit_ln(const int* __restrict__ inputs, const float* __restrict__ emb,
              const float* __restrict__ g1, const float* __restrict__ bb1,
              float* __restrict__ z, u16* __restrict__ zn)
{
  __shared__ float sh[4];
  const int row = blockIdx.x;
  const int b = row >> 10, q = row & 1023;
  const int id = inputs[(long)b*8192 + 7168 + q];
  const int tid = threadIdx.x;
  float4 t = *(const float4*)(emb + (long)id*1024 + tid*4);
  *(float4*)(z + (long)row*1024 + tid*4) = t;
  float s = t.x+t.y+t.z+t.w;
  float m = block_reduce(s, 0, sh) * (1.f/1024.f);
  float d0=t.x-m, d1=t.y-m, d2=t.z-m, d3=t.w-m;
  float s2 = d0*d0+d1*d1+d2*d2+d3*d3;
  float var = block_reduce(s2, 0, sh) * (1.f/1024.f);
  float r = rsqrtf(var + 1e-5f);
  const int c = tid*4;
  float4 g = *(const float4*)(g1+c);
  float4 bb = *(const float4*)(bb1+c);
  u16x4 pk;
  pk[0]=f2b(d0*r*g.x+bb.x); pk[1]=f2b(d1*r*g.y+bb.y);
  pk[2]=f2b(d2*r*g.z+bb.z); pk[3]=f2b(d3*r*g.w+bb.w);
  *(u16x4*)(zn + (long)row*1024 + c) = pk;
}

// ---------------------------------------------------------------------------
// Masked softmax over a bf16 row of LEN; in-place bf16, 16B/lane loads.
// ---------------------------------------------------------------------------
template<int LEN>
__global__ __launch_bounds__(256)
void softmax16(u16* __restrict__ S, int qmask, int off)
{
  constexpr int PER = LEN/256;           // 32
  __shared__ float sh[4];
  const long row = blockIdx.x;
  const int qi = ((int)row) & qmask;
  const int lim = off + qi;
  u16* srow = S + row*(long)LEN;
  const int tid = threadIdx.x;
  float v[PER];
  float mx = -3.0e38f;
  #pragma unroll
  for (int i=0;i<PER/8;i++){
    int j0 = i*2048 + tid*8;
    u16x8 t = *(const u16x8*)(srow + j0);
    #pragma unroll
    for (int k=0;k<8;k++){
      float val = (j0+k <= lim) ? b2f(t[k]) : -3.0e38f;
      v[i*8+k] = val;
      mx = fmaxf(mx, val);
    }
  }
  float M = block_reduce(mx, 1, sh);
  float s = 0.f;
  #pragma unroll
  for (int i=0;i<PER;i++){ float e = __expf(v[i]-M); v[i]=e; s+=e; }
  float T = block_reduce(s, 0, sh);
  float inv = 1.0f / T;
  #pragma unroll
  for (int i=0;i<PER/8;i++){
    int j0 = i*2048 + tid*8;
    u16x8 pk;
    #pragma unroll
    for (int k=0;k<8;k++) pk[k] = f2b(v[i*8+k]*inv);
    *(u16x8*)(srow + j0) = pk;
  }
}

// ---------------------------------------------------------------------------
__global__ __launch_bounds__(256)
void pack_bias(const float* __restrict__ bq, const float* __restrict__ bk,
               const float* __restrict__ bv, float* __restrict__ qkvb,
               const float* __restrict__ cbk, const float* __restrict__ cbv,
               float* __restrict__ kvb)
{
  const int l = blockIdx.y;
  const int i = blockIdx.x*256 + threadIdx.x;   // 0..3071
  float v;
  if (i < 1024)      v = bq[l*1024 + i];
  else if (i < 2048) v = bk[l*1024 + i - 1024];
  else               v = bv[l*1024 + i - 2048];
  qkvb[l*3072 + i] = v;
  if (l == 0 && i < 2048)
    kvb[i] = (i < 1024) ? cbk[i] : cbv[i - 1024];
}

// ---------------------------------------------------------------------------
__global__ __launch_bounds__(256)
void transpose_w(const float* cwq, const float* cwk, const float* cwv,
                 const float* cwo, const float* cw1, const float* cw2,
                 const float* swq, const float* swk, const float* swv,
                 const float* swo, const float* sw1, const float* sw2,
                 u16* __restrict__ wT)
{
  const int slot = blockIdx.z;
  const float* W;
  switch (slot) {
    case 0:  W = cwq; break;  case 1:  W = cwk; break;
    case 2:  W = cwv; break;  case 3:  W = cwo; break;
    case 4:  W = cw1; break;  case 5:  W = cw2; break;
    case 6:  W = swq; break;  case 7:  W = swk; break;
    case 8:  W = swv; break;  case 9:  W = swo; break;
    case 10: W = sw1; break;  case 11: W = sw2; break;
    case 12: W = swq + 1048576; break; case 13: W = swk + 1048576; break;
    case 14: W = swv + 1048576; break; case 15: W = swo + 1048576; break;
    case 16: W = sw1 + 1048576; break; default: W = sw2 + 1048576; break;
  }
  u16* T = wT + (long)slot*1048576;
  __shared__ float t[32][33];
  const int tx = threadIdx.x & 31, ty = threadIdx.x >> 5;
  const int k0 = blockIdx.x*32, n0 = blockIdx.y*32;
  #pragma unroll
  for (int i=0;i<4;i++)
    t[ty + i*8][tx] = W[(long)(k0 + ty + i*8)*1024 + n0 + tx];
  __syncthreads();
  #pragma unroll
  for (int i=0;i<4;i++)
    T[(long)(n0 + ty + i*8)*1024 + k0 + tx] = f2b(t[tx][ty + i*8]);
}

// ---------------------------------------------------------------------------
extern "C" void kernel_launch(void* const* d_in, const int* in_sizes, int n_in,
                              void* d_out, int out_size, void* d_ws, size_t ws_size,
                              hipStream_t stream)
{
  (void)in_sizes; (void)n_in; (void)out_size;
  const int*   inputs   = (const int*)  d_in[0];
  const float* emb      = (const float*)d_in[1];
  const float* c_lnq_g  = (const float*)d_in[2];
  const float* c_lnq_b  = (const float*)d_in[3];
  const float* c_lnkv_g = (const float*)d_in[4];
  const float* c_lnkv_b = (const float*)d_in[5];
  const float* c_bq = (const float*)d_in[7];
  const float* c_bk = (const float*)d_in[9];
  const float* c_bv = (const float*)d_in[11];
  const float* c_bo = (const float*)d_in[13];
  const float* c_ln2_g = (const float*)d_in[14];
  const float* c_ln2_b = (const float*)d_in[15];
  const float* c_b1 = (const float*)d_in[17];
  const float* c_b2 = (const float*)d_in[19];
  const float* s_lnq_g = (const float*)d_in[20];
  const float* s_lnq_b = (const float*)d_in[21];
  const float* s_bq = (const float*)d_in[23];
  const float* s_bk = (const float*)d_in[25];
  const float* s_bv = (const float*)d_in[27];
  const float* s_bo = (const float*)d_in[29];
  const float* s_ln2_g = (const float*)d_in[30];
  const float* s_ln2_b = (const float*)d_in[31];
  const float* s_b1 = (const float*)d_in[33];
  const float* s_b2 = (const float*)d_in[35];

  const long MB1 = 1048576;
  const long PB  = 8388608;       // P elements per batch (1024 x 8192 u16)

  char* wsb = (char*)d_ws;
  size_t off = 0;
  auto alloc = [&](size_t n)->char* {
    char* p = wsb + off; off += (n + 255) & ~(size_t)255; return p;
  };
  u16*   wT       = (u16*)  alloc((size_t)18*1048576*2);   // 36 MB
  u16*   Ktab     = (u16*)  alloc((size_t)8192*1024*2);    // 16 MB ┐ adjacent
  u16*   Vtab     = (u16*)  alloc((size_t)8192*1024*2);    // 16 MB ┘
  u16*   VTcb     = (u16*)  alloc((size_t)1024*8192*2);    // 16 MB
  u16*   Q        = (u16*)  alloc((size_t)4096*1024*2);    // 8 MB
  u16*   O        = (u16*)  alloc((size_t)4096*1024*2);    // 8 MB
  u16*   Opart16  = (u16*)  alloc((size_t)8*1024*1024*4);  // 32 MB region
  u16*   P4       = (u16*)  alloc((size_t)4*1024*8192*2);  // 64 MB: P (cross)
  // aliases inside P4 (all dead while P is live):
  u16*   lnkv_tab = P4;                                    // 16 MB
  u16*   zn       = P4 +  8*MB1;                           // 8 MB
  u16*   h1       = P4 + 12*MB1;                           // 8 MB
  u16*   Qs       = P4 + 16*MB1;                           // 8 MB
  u16*   Ks       = P4 + 20*MB1;                           // 8 MB
  u16*   VsT      = P4 + 24*MB1;                           // 8 MB
  float* qkvb     = (float*)alloc((size_t)2*3072*4);
  float* kvb      = (float*)alloc((size_t)2048*4);
  float* z        = (float*)d_out;

  if (ws_size < off) return;  // ws too small: leave output zeroed (diagnostic)

  // ---- setup -------------------------------------------------------------
  transpose_w<<<dim3(32,32,18), 256, 0, stream>>>(
      (const float*)d_in[6], (const float*)d_in[8], (const float*)d_in[10],
      (const float*)d_in[12], (const float*)d_in[16], (const float*)d_in[18],
      (const float*)d_in[22], (const float*)d_in[24], (const float*)d_in[26],
      (const float*)d_in[28], (const float*)d_in[32], (const float*)d_in[34], wT);
  pack_bias<<<dim3(12,2), 256, 0, stream>>>(s_bq, s_bk, s_bv, qkvb,
                                            c_bk, c_bv, kvb);
  ln_kernel<0><<<8192, 256, 0, stream>>>(emb, c_lnkv_g, c_lnkv_b,
                                         nullptr, nullptr, lnkv_tab, nullptr);
  zinit_ln<<<4096, 256, 0, stream>>>(inputs, emb, c_lnq_g, c_lnq_b, z, zn);

  // ---- cross attention ---------------------------------------------------
  // K/V vocab tables (z over adjacent wk|wv slots), MT=4 (4/CU)
  gemm_nt<0,false,4,0><<<dim3(64,8,2),256,0,stream>>>(
      lnkv_tab, 0,0,1, 1024,
      wT + 1*MB1, nullptr, 0, MB1,0,1, 1024,
      kvb, 1024,
      Ktab, PB,0,1, 1024, 1024);
  // Q projection, MT=1 (1024 blocks = 4/CU)
  gemm_nt<0,false,1,0><<<dim3(128,8,1),256,0,stream>>>(
      zn, 0,0,1, 1024,
      wT + 0*MB1, nullptr, 0, 0,0,1, 1024,
      c_bq, 0,
      Q, 0,0,1, 1024, 1024);
  // scores for ALL 4 batches (bf16, *1/32), MT=4, SWAP=1 (B-panel L2 reuse:
  // FETCH 70 MB ~= traffic floor, measured rounds 10-11)
  gemm_nt<5,true,4,1><<<dim3(64,8,4),256,0,stream>>>(
      Q, MB1,0,1, 1024,
      Ktab, inputs, 8192, 0,0,1, 1024,
      nullptr, 0,
      P4, PB,0,1, 8192, 1024);
  softmax16<8192><<<4096, 256, 0, stream>>>(P4, 1023, 7168);
  for (int b = 0; b < 4; ++b) {
    gather_T<<<dim3(128,16),256,0,stream>>>(Vtab, inputs + (long)b*8192, VTcb);
    // split-K PV: 8 chunks of K=1024, bf16 partials, 1024 blocks (4/CU)
    gemm_nt<6,false,2,0><<<dim3(16,8,8),256,0,stream>>>(
        P4 + (long)b*PB, 0,1024,8, 8192,
        VTcb, nullptr, 0, 0,1024,8, 8192,
        nullptr, 0,
        Opart16, 1048576,0,1, 1024, 1024);
    reduce8b<<<1024,256,0,stream>>>(Opart16, O + (long)b*MB1);
  }
  // z += O @ wo^T + bo, MT=1
  gemm_nt<2,false,1,0><<<dim3(128,8,1),256,0,stream>>>(
      O, 0,0,1, 1024,
      wT + 3*MB1, nullptr, 0, 0,0,1, 1024,
      c_bo, 0,
      z, 0,0,1, 1024, 1024);

  // ---- central FFN (MT=1) ------------------------------------------------
  ln_kernel<0><<<4096,256,0,stream>>>(z, c_ln2_g, c_ln2_b, nullptr,nullptr, zn, nullptr);
  gemm_nt<1,false,1,0><<<dim3(128,8,1),256,0,stream>>>(
      zn, 0,0,1, 1024,
      wT + 4*MB1, nullptr, 0, 0,0,1, 1024,
      c_b1, 0,
      h1, 0,0,1, 1024, 1024);
  gemm_nt<2,false,1,0><<<dim3(128,8,1),256,0,stream>>>(
      h1, 0,0,1, 1024,
      wT + 5*MB1, nullptr, 0, 0,0,1, 1024,
      c_b2, 0,
      z, 0,0,1, 1024, 1024);

  // ---- self-attention blocks (NB*L = 4, l = 0,1,0,1) ---------------------
  for (int it = 0; it < 4; ++it) {
    const int l = it & 1;
    const u16* wqkv = wT + (size_t)(6 + l*6)*MB1;
    const u16* wo = wT + (size_t)(6 + l*6 + 3)*MB1;
    const u16* w1 = wT + (size_t)(6 + l*6 + 4)*MB1;
    const u16* w2 = wT + (size_t)(6 + l*6 + 5)*MB1;

    ln_kernel<0><<<4096,256,0,stream>>>(z, s_lnq_g + l*1024, s_lnq_b + l*1024,
                                        nullptr,nullptr, zn, nullptr);
    gemm_qkv<<<dim3(64,24),256,0,stream>>>(zn, wqkv, qkvb + l*3072, Qs, Ks, VsT);
    flash_self<<<dim3(32,16),256,0,stream>>>(Qs, Ks, VsT, O);
    gemm_nt<2,false,1,0><<<dim3(128,8,1),256,0,stream>>>(
        O, 0,0,1, 1024,  wo, nullptr, 0, 0,0,1, 1024,
        s_bo + l*1024, 0,
        z, 0,0,1, 1024, 1024);

    ln_kernel<0><<<4096,256,0,stream>>>(z, s_ln2_g + l*1024, s_ln2_b + l*1024,
                                        nullptr,nullptr, zn, nullptr);
    gemm_nt<1,false,1,0><<<dim3(128,8,1),256,0,stream>>>(
        zn, 0,0,1, 1024,  w1, nullptr, 0, 0,0,1, 1024,
        s_b1 + l*1024, 0,
        h1, 0,0,1, 1024, 1024);
    gemm_nt<2,false,1,0><<<dim3(128,8,1),256,0,stream>>>(
        h1, 0,0,1, 1024,  w2, nullptr, 0, 0,0,1, 1024,
        s_b2 + l*1024, 0,
        z, 0,0,1, 1024, 1024);
  }
}

// Round 15
// 1037.192 us; speedup vs baseline: 1.0181x; 1.0181x over previous
//
#include <hip/hip_runtime.h>

typedef unsigned short u16;
typedef float f32x4 __attribute__((ext_vector_type(4)));
typedef short s16x8 __attribute__((ext_vector_type(8)));
typedef unsigned short u16x4 __attribute__((ext_vector_type(4)));
typedef unsigned short u16x8 __attribute__((ext_vector_type(8)));

__device__ __forceinline__ u16 f2b(float x){
  union{float f; unsigned u;} a; a.f=x;
  return (u16)((a.u + 0x7fffu + ((a.u>>16)&1u))>>16);
}
__device__ __forceinline__ float b2f(u16 x){
  union{unsigned u; float f;} a; a.u = ((unsigned)x)<<16; return a.f;
}

// Async global->LDS, 16B per lane. Dest wave-uniform base; HW adds lane*16.
__device__ __forceinline__ void gload16(const u16* g, u16* l){
  __builtin_amdgcn_global_load_lds(
      (const __attribute__((address_space(1))) void*)g,
      (__attribute__((address_space(3))) void*)l, 16, 0, 0);
}

__device__ __forceinline__ float block_reduce(float v, int op, float* sh){
  #pragma unroll
  for (int o=32;o>0;o>>=1){
    float t = __shfl_down(v, o);
    v = op ? fmaxf(v,t) : v+t;
  }
  int w = threadIdx.x>>6;
  if ((threadIdx.x&63)==0) sh[w]=v;
  __syncthreads();
  float r = op ? fmaxf(fmaxf(sh[0],sh[1]),fmaxf(sh[2],sh[3]))
               : (sh[0]+sh[1]+sh[2]+sh[3]);
  __syncthreads();
  return r;
}

// ---------------------------------------------------------------------------
// NT GEMM: C[m][n] = sum_k A[m][k] * B[n][k]  (+bias[n]). Optional row gather
// on B. Tile = (MT*32) x 128, BK=64, 256 thr. global_load_lds staging, linear
// LDS, both-sides XOR swizzle. MFMA computes C^T -> 4 consecutive n per lane.
// MT ladder (measured rounds 8-14, 2-barrier structure): MT=4 at >=4
// blocks/CU (755-800 TF); MT=2 at 2/CU for the N=1024 fleet; MT=1 and MT=8
// both measured WORSE (rounds 14, 12). This is the structure's optimum.
// SWAP=1 (x indexes n-tile): only when B-panel reuse dominates (gather-scores).
// EPI: 0 bf16+bias, 1 sqrelu bf16+bias, 2 f32 residual += (+bias),
//      3 f32 store, 5 bf16 store * (1/32) (cross scores), 6 bf16 store plain
// ---------------------------------------------------------------------------
template<int EPI, bool BG, int MT, int SWAP>
__global__ __launch_bounds__(256)
void gemm_nt(const u16* __restrict__ A,
             long a_s1, long a_s2, int azd, int lda,
             const u16* __restrict__ B, const int* __restrict__ bidx,
             int bidx_zs, long b_s1, long b_s2, int bzd, int ldb,
             const float* __restrict__ bias, int bias_zs,
             void* __restrict__ Cv, long c_s1, long c_s2, int czd, int ldc,
             int K)
{
  __shared__ u16 lA[MT*32*64];
  __shared__ u16 lB[128*64];
  const int tid = threadIdx.x;
  const int z = blockIdx.z;
  const int m0 = (SWAP ? blockIdx.y : blockIdx.x) * (MT*32);
  const int n0 = (SWAP ? blockIdx.x : blockIdx.y) * 128;
  const u16* Ab = A + (long)(z/azd)*a_s1 + (long)(z%azd)*a_s2;
  const u16* Bb = B + (long)(z/bzd)*b_s1 + (long)(z%bzd)*b_s2;
  const int* bi = BG ? (bidx + (long)z*bidx_zs) : nullptr;

  const int w = tid >> 6, lane = tid & 63;
  const int wr = w >> 1, wc = w & 1;
  const int lm = lane >> 4, ln = lane & 15;

  f32x4 acc[MT][4];
  #pragma unroll
  for (int i=0;i<MT;i++)
    #pragma unroll
    for (int j=0;j<4;j++) acc[i][j] = (f32x4){0.f,0.f,0.f,0.f};

  for (int kt = 0; kt < K; kt += 64) {
    __syncthreads();
    #pragma unroll
    for (int i = 0; i < MT; i++) {
      int c = i*256 + tid;
      int r = c >> 3;
      int kc = ((c & 7) ^ (r & 7)) << 3;       // inverse-swizzled source chunk
      gload16(Ab + (long)(m0+r)*lda + kt + kc, &lA[(i*256 + (tid & 192))*8]);
    }
    #pragma unroll
    for (int i = 0; i < 4; i++) {
      int c = i*256 + tid;
      int r = c >> 3;
      int kc = ((c & 7) ^ (r & 7)) << 3;
      long brow = BG ? (long)bi[n0 + r] : (long)(n0 + r);
      gload16(Bb + brow*(long)ldb + kt + kc, &lB[(i*256 + (tid & 192))*8]);
    }
    __syncthreads();
    #pragma unroll
    for (int kk = 0; kk < 2; kk++) {
      const int chunk = kk*4 + lm;
      const int ksw = ((chunk ^ (ln & 7)) << 3);
      s16x8 af[MT], bf[4];
      #pragma unroll
      for (int i=0;i<MT;i++) af[i] = *(const s16x8*)(&lA[(wr*(MT*16) + i*16 + ln)*64 + ksw]);
      #pragma unroll
      for (int j=0;j<4;j++) bf[j] = *(const s16x8*)(&lB[(wc*64 + j*16 + ln)*64 + ksw]);
      #pragma unroll
      for (int i=0;i<MT;i++)
        #pragma unroll
        for (int j=0;j<4;j++)   // swapped operands -> C^T fragment layout
          acc[i][j] = __builtin_amdgcn_mfma_f32_16x16x32_bf16(bf[j], af[i], acc[i][j], 0,0,0);
    }
  }

  const long co = (long)(z/czd)*c_s1 + (long)(z%czd)*c_s2;
  const float* biasp = (EPI==3 || EPI==5 || EPI==6) ? nullptr : (bias + (long)z*bias_zs);
  #pragma unroll
  for (int i=0;i<MT;i++) {
    const int m = m0 + wr*(MT*16) + i*16 + ln;     // col of C^T = m
    #pragma unroll
    for (int j=0;j<4;j++) {
      const int nb = n0 + wc*64 + j*16 + lm*4;     // row of C^T = n (4 consec)
      f32x4 v = acc[i][j];
      if constexpr (EPI == 3) {
        *(f32x4*)((float*)Cv + co + (long)m*ldc + nb) = v;
      } else if constexpr (EPI == 5) {
        u16x4 pk;
        pk[0]=f2b(v[0]*0.03125f); pk[1]=f2b(v[1]*0.03125f);
        pk[2]=f2b(v[2]*0.03125f); pk[3]=f2b(v[3]*0.03125f);
        *(u16x4*)((u16*)Cv + co + (long)m*ldc + nb) = pk;
      } else if constexpr (EPI == 6) {
        u16x4 pk;
        pk[0]=f2b(v[0]); pk[1]=f2b(v[1]); pk[2]=f2b(v[2]); pk[3]=f2b(v[3]);
        *(u16x4*)((u16*)Cv + co + (long)m*ldc + nb) = pk;
      } else {
        float4 vb = *(const float4*)(biasp + nb);
        if constexpr (EPI == 2) {
          float* Cf = (float*)Cv + co + (long)m*ldc + nb;
          f32x4 old = *(f32x4*)Cf;
          old[0] += v[0]+vb.x; old[1] += v[1]+vb.y;
          old[2] += v[2]+vb.z; old[3] += v[3]+vb.w;
          *(f32x4*)Cf = old;
        } else {
          float x0 = v[0]+vb.x, x1 = v[1]+vb.y, x2 = v[2]+vb.z, x3 = v[3]+vb.w;
          if constexpr (EPI == 1) {
            x0 = x0>0.f ? x0*x0 : 0.f; x1 = x1>0.f ? x1*x1 : 0.f;
            x2 = x2>0.f ? x2*x2 : 0.f; x3 = x3>0.f ? x3*x3 : 0.f;
          }
          u16x4 pk; pk[0]=f2b(x0); pk[1]=f2b(x1); pk[2]=f2b(x2); pk[3]=f2b(x3);
          *(u16x4*)((u16*)Cv + co + (long)m*ldc + nb) = pk;
        }
      }
    }
  }
}

// ---------------------------------------------------------------------------
// Fused QKV projection, 64x128 tiles. Grid (64,24): x = m-tile (A-co-locate).
// ---------------------------------------------------------------------------
__global__ __launch_bounds__(256)
void gemm_qkv(const u16* __restrict__ A, const u16* __restrict__ Bw,
              const float* __restrict__ bias,
              u16* __restrict__ Qs, u16* __restrict__ Ks, u16* __restrict__ VsT)
{
  __shared__ u16 lA[64*64];
  __shared__ u16 lB[128*64];
  const int tid = threadIdx.x;
  const int m0 = blockIdx.x * 64;
  const int n0 = blockIdx.y * 128;
  const int w = tid >> 6, lane = tid & 63;
  const int wr = w >> 1, wc = w & 1;
  const int lm = lane >> 4, ln = lane & 15;
  const bool tp = (n0 < 2048);

  f32x4 acc[2][4];
  #pragma unroll
  for (int i=0;i<2;i++)
    #pragma unroll
    for (int j=0;j<4;j++) acc[i][j] = (f32x4){0.f,0.f,0.f,0.f};

  for (int kt = 0; kt < 1024; kt += 64) {
    __syncthreads();
    #pragma unroll
    for (int i = 0; i < 2; i++) {
      int c = i*256 + tid;
      int r = c >> 3;
      int kc = ((c & 7) ^ (r & 7)) << 3;
      gload16(A + (long)(m0+r)*1024 + kt + kc, &lA[(i*256 + (tid & 192))*8]);
    }
    #pragma unroll
    for (int i = 0; i < 4; i++) {
      int c = i*256 + tid;
      int r = c >> 3;
      int kc = ((c & 7) ^ (r & 7)) << 3;
      gload16(Bw + (long)(n0+r)*1024 + kt + kc, &lB[(i*256 + (tid & 192))*8]);
    }
    __syncthreads();
    #pragma unroll
    for (int kk = 0; kk < 2; kk++) {
      const int chunk = kk*4 + lm;
      const int ksw = ((chunk ^ (ln & 7)) << 3);
      s16x8 af[2], bf[4];
      #pragma unroll
      for (int i=0;i<2;i++) af[i] = *(const s16x8*)(&lA[(wr*32 + i*16 + ln)*64 + ksw]);
      #pragma unroll
      for (int j=0;j<4;j++) bf[j] = *(const s16x8*)(&lB[(wc*64 + j*16 + ln)*64 + ksw]);
      if (tp) {
        #pragma unroll
        for (int i=0;i<2;i++)
          #pragma unroll
          for (int j=0;j<4;j++)
            acc[i][j] = __builtin_amdgcn_mfma_f32_16x16x32_bf16(bf[j], af[i], acc[i][j], 0,0,0);
      } else {
        #pragma unroll
        for (int i=0;i<2;i++)
          #pragma unroll
          for (int j=0;j<4;j++)
            acc[i][j] = __builtin_amdgcn_mfma_f32_16x16x32_bf16(af[i], bf[j], acc[i][j], 0,0,0);
      }
    }
  }

  if (tp) {
    u16* dst = (n0 < 1024) ? Qs : Ks;
    #pragma unroll
    for (int i=0;i<2;i++) {
      const int m = m0 + wr*32 + i*16 + ln;
      #pragma unroll
      for (int j=0;j<4;j++) {
        const int gn = n0 + wc*64 + j*16 + lm*4;
        float4 vb = *(const float4*)(bias + gn);
        f32x4 v = acc[i][j];
        u16x4 pk;
        pk[0]=f2b(v[0]+vb.x); pk[1]=f2b(v[1]+vb.y);
        pk[2]=f2b(v[2]+vb.z); pk[3]=f2b(v[3]+vb.w);
        *(u16x4*)(dst + (long)m*1024 + (gn & 1023)) = pk;
      }
    }
  } else {
    #pragma unroll
    for (int i=0;i<2;i++) {
      const int gmb = m0 + wr*32 + i*16 + lm*4;
      #pragma unroll
      for (int j=0;j<4;j++) {
        const int gn = n0 + wc*64 + j*16 + ln;
        const float bb = bias[gn];
        f32x4 v = acc[i][j];
        long addr = (long)(gmb >> 10)*1048576 + (long)(gn - 2048)*1024 + (gmb & 1023);
        u16x4 pk;
        #pragma unroll
        for (int r=0;r<4;r++) pk[r] = f2b(v[r] + bb);
        *(u16x4*)(VsT + addr) = pk;
      }
    }
  }
}

// ---------------------------------------------------------------------------
// Flash self-attention: causal, H=8, d=128. T14 reg-prefetch + T5 setprio +
// T13 defer-max.
// ---------------------------------------------------------------------------
__global__ __launch_bounds__(256)
void flash_self(const u16* __restrict__ Qs, const u16* __restrict__ Ks,
                const u16* __restrict__ VsT, u16* __restrict__ O)
{
  __shared__ u16 lK[64][128];
  __shared__ u16 lV[128][64];
  __shared__ u16 lP[4][16][64];

  const int tid = threadIdx.x;
  const int w = tid >> 6, lane = tid & 63;
  const int g = lane >> 4, ln = lane & 15;
  const int bh = blockIdx.x;
  const int b = bh >> 3, h = bh & 7;
  const int y = blockIdx.y;
  const int qt = (y < 8) ? (15 - y) : (y - 8);

  const long qrow0 = (long)b*1024 + qt*64 + w*16;
  const u16* Qp = Qs + qrow0*1024 + h*128;
  const u16* Kp = Ks + (long)b*1048576 + h*128;
  const u16* Vp = VsT + (long)b*1048576 + (long)h*131072;

  s16x8 bq[4];
  #pragma unroll
  for (int ks=0;ks<4;ks++)
    bq[ks] = *(const s16x8*)(Qp + (long)ln*1024 + ks*32 + g*8);

  f32x4 ao[8];
  #pragma unroll
  for (int i=0;i<8;i++) ao[i] = (f32x4){0.f,0.f,0.f,0.f};
  float mrun = -3.0e38f, lrun = 0.f;
  const int qc = qt*64 + w*16 + ln;

  const int nt = qt + 1;

  s16x8 pK[4], pV[4];
  #pragma unroll
  for (int i=0;i<4;i++){
    int c = i*256 + tid;
    int rr = c >> 4, d8 = c & 15;
    pK[i] = *(const s16x8*)(Kp + (long)rr*1024 + d8*8);
    int dd = c >> 3, k8 = c & 7;
    pV[i] = *(const s16x8*)(Vp + (long)dd*1024 + k8*8);
  }

  for (int kt = 0; kt < nt; ++kt) {
    __syncthreads();
    #pragma unroll
    for (int i=0;i<4;i++){
      int c = i*256 + tid;
      int rr = c >> 4, d8 = c & 15;
      *(s16x8*)(&lK[rr][(d8 ^ (rr&7))*8]) = pK[i];
      int dd = c >> 3, k8 = c & 7;
      *(s16x8*)(&lV[dd][(k8 ^ (dd&7))*8]) = pV[i];
    }
    __syncthreads();
    if (kt+1 < nt){
      const u16* src  = Kp + (long)((kt+1)*64)*1024;
      const u16* vsrc = Vp + (kt+1)*64;
      #pragma unroll
      for (int i=0;i<4;i++){
        int c = i*256 + tid;
        int rr = c >> 4, d8 = c & 15;
        pK[i] = *(const s16x8*)(src + (long)rr*1024 + d8*8);
        int dd = c >> 3, k8 = c & 7;
        pV[i] = *(const s16x8*)(vsrc + (long)dd*1024 + k8*8);
      }
    }

    f32x4 as_[4];
    #pragma unroll
    for (int i=0;i<4;i++) as_[i] = (f32x4){0.f,0.f,0.f,0.f};
    __builtin_amdgcn_s_setprio(1);
    #pragma unroll
    for (int ks=0;ks<4;ks++){
      #pragma unroll
      for (int mi=0;mi<4;mi++){
        s16x8 ak = *(const s16x8*)(&lK[16*mi + ln][((g + 4*ks) ^ (ln&7))*8]);
        as_[mi] = __builtin_amdgcn_mfma_f32_16x16x32_bf16(ak, bq[ks], as_[mi], 0,0,0);
      }
    }
    __builtin_amdgcn_s_setprio(0);

    const int kkb = kt*64 + 4*g;
    float mx = -3.0e38f;
    #pragma unroll
    for (int mi=0;mi<4;mi++)
      #pragma unroll
      for (int r=0;r<4;r++){
        float s = as_[mi][r] * 0.08838834764831845f;
        if (kkb + 16*mi + r > qc) s = -3.0e38f;
        as_[mi][r] = s;
        mx = fmaxf(mx, s);
      }
    mx = fmaxf(mx, __shfl_xor(mx, 16));
    mx = fmaxf(mx, __shfl_xor(mx, 32));
    if (!__all(mx - mrun <= 8.0f)) {
      float mnew = fmaxf(mrun, mx);
      float alpha = __expf(mrun - mnew);
      lrun *= alpha;
      #pragma unroll
      for (int mi=0;mi<8;mi++)
        #pragma unroll
        for (int r=0;r<4;r++)
          ao[mi][r] *= alpha;
      mrun = mnew;
    }
    float sum = 0.f;
    #pragma unroll
    for (int mi=0;mi<4;mi++){
      u16x4 pk;
      #pragma unroll
      for (int r=0;r<4;r++){
        float p = __expf(as_[mi][r] - mrun);
        sum += p;
        pk[r] = f2b(p);
      }
      *(u16x4*)(&lP[w][ln][(((2*mi + (g>>1)) ^ (ln&7))<<3) + (g&1)*4]) = pk;
    }
    sum += __shfl_xor(sum, 16);
    sum += __shfl_xor(sum, 32);
    lrun += sum;

    __builtin_amdgcn_s_setprio(1);
    #pragma unroll
    for (int ks=0;ks<2;ks++){
      s16x8 bp = *(const s16x8*)(&lP[w][ln][((4*ks + g) ^ (ln&7))*8]);
      #pragma unroll
      for (int mi=0;mi<8;mi++){
        s16x8 av = *(const s16x8*)(&lV[16*mi + ln][((g + 4*ks) ^ (ln&7))*8]);
        ao[mi] = __builtin_amdgcn_mfma_f32_16x16x32_bf16(av, bp, ao[mi], 0,0,0);
      }
    }
    __builtin_amdgcn_s_setprio(0);
  }

  const float inv = 1.f/lrun;
  #pragma unroll
  for (int mi=0;mi<8;mi++){
    u16x4 pk;
    #pragma unroll
    for (int r=0;r<4;r++) pk[r] = f2b(ao[mi][r]*inv);
    *(u16x4*)(O + (qrow0 + ln)*1024 + h*128 + 16*mi + 4*g) = pk;
  }
}

// ---------------------------------------------------------------------------
// Gather-transpose: VT[d][s] = Vtab[idx[s]][d].
// ---------------------------------------------------------------------------
__global__ __launch_bounds__(256)
void gather_T(const u16* __restrict__ Vtab, const int* __restrict__ idx,
              u16* __restrict__ VT)
{
  __shared__ u16 t[64][72];
  const int s0 = blockIdx.x*64, d0 = blockIdx.y*64;
  const int tr = threadIdx.x>>3, tc = threadIdx.x&7;
  #pragma unroll
  for (int i=0;i<2;i++){
    int s = tr + i*32;
    long row = idx[s0+s];
    *(s16x8*)(&t[s][tc*8]) = *(const s16x8*)(Vtab + row*1024 + d0 + tc*8);
  }
  __syncthreads();
  #pragma unroll
  for (int i=0;i<2;i++){
    int d = tr + i*32;
    u16 out[8];
    #pragma unroll
    for (int j=0;j<8;j++) out[j] = t[tc*8+j][d];
    *(s16x8*)(VT + (long)(d0+d)*8192 + s0 + tc*8) = *(s16x8*)out;
  }
}

// ---------------------------------------------------------------------------
// Sum 8 bf16 split-K partial planes (1M elems each) -> bf16.
// ---------------------------------------------------------------------------
__global__ __launch_bounds__(256)
void reduce8b(const u16* __restrict__ Pp, u16* __restrict__ Ob){
  long i = ((long)blockIdx.x*256 + threadIdx.x)*4;
  float s0=0.f, s1=0.f, s2=0.f, s3=0.f;
  #pragma unroll
  for (int p=0;p<8;p++){
    u16x4 t = *(const u16x4*)(Pp + (long)p*1048576 + i);
    s0 += b2f(t[0]); s1 += b2f(t[1]); s2 += b2f(t[2]); s3 += b2f(t[3]);
  }
  u16x4 pk; pk[0]=f2b(s0); pk[1]=f2b(s1); pk[2]=f2b(s2); pk[3]=f2b(s3);
  *(u16x4*)(Ob + i) = pk;
}

// ---------------------------------------------------------------------------
template<int TWO>
__global__ __launch_bounds__(256)
void ln_kernel(const float* __restrict__ X,
               const float* __restrict__ g1, const float* __restrict__ bb1,
               const float* __restrict__ g2, const float* __restrict__ bb2,
               u16* __restrict__ o1, u16* __restrict__ o2)
{
  __shared__ float sh[4];
  const long row = blockIdx.x;
  const int tid = threadIdx.x;
  const float* x = X + row*1024;
  float4 t = *(const float4*)(x + tid*4);
  float s = t.x+t.y+t.z+t.w;
  float m = block_reduce(s, 0, sh) * (1.f/1024.f);
  float d0=t.x-m, d1=t.y-m, d2=t.z-m, d3=t.w-m;
  float s2 = d0*d0+d1*d1+d2*d2+d3*d3;
  float var = block_reduce(s2, 0, sh) * (1.f/1024.f);
  float r = rsqrtf(var + 1e-5f);
  const int c = tid*4;
  {
    float4 g = *(const float4*)(g1+c);
    float4 b = *(const float4*)(bb1+c);
    u16x4 pk;
    pk[0]=f2b(d0*r*g.x+b.x); pk[1]=f2b(d1*r*g.y+b.y);
    pk[2]=f2b(d2*r*g.z+b.z); pk[3]=f2b(d3*r*g.w+b.w);
    *(u16x4*)(o1 + row*1024 + c) = pk;
  }
  if constexpr (TWO) {
    float4 g = *(const float4*)(g2+c);
    float4 b = *(const float4*)(bb2+c);
    u16x4 pk;
    pk[0]=f2b(d0*r*g.x+b.x); pk[1]=f2b(d1*r*g.y+b.y);
    pk[2]=f2b(d2*r*g.z+b.z); pk[3]=f2b(d3*r*g.w+b.w);
    *(u16x4*)(o2 + row*1024 + c) = pk;
  }
}

// ---------------------------------------------------------------------------
// Fused z-init + LN(c_lnq): z[row] = emb[idx]; zn[row] = LN(z[row]).
// ---------------------------------------------------------------------------
__global__ __launch_bounds__(256)
void zinit_ln(const int* __restrict__ inputs, const float* __restrict__ emb,
              const float* __restrict__ g1, const float* __restrict__ bb1,
              float* __restrict__ z, u16* __restrict__ zn)
{
  __shared__ float sh[4];
  const int row = blockIdx.x;
  const int b = row >> 10, q = row & 1023;
  const int id = inputs[(long)b*8192 + 7168 + q];
  const int tid = threadIdx.x;
  float4 t = *(const float4*)(emb + (long)id*1024 + tid*4);
  *(float4*)(z + (long)row*1024 + tid*4) = t;
  float s = t.x+t.y+t.z+t.w;
  float m = block_reduce(s, 0, sh) * (1.f/1024.f);
  float d0=t.x-m, d1=t.y-m, d2=t.z-m, d3=t.w-m;
  float s2 = d0*d0+d1*d1+d2*d2+d3*d3;
  float var = block_reduce(s2, 0, sh) * (1.f/1024.f);
  float r = rsqrtf(var + 1e-5f);
  const int c = tid*4;
  float4 g = *(const float4*)(g1+c);
  float4 bb = *(const float4*)(bb1+c);
  u16x4 pk;
  pk[0]=f2b(d0*r*g.x+bb.x); pk[1]=f2b(d1*r*g.y+bb.y);
  pk[2]=f2b(d2*r*g.z+bb.z); pk[3]=f2b(d3*r*g.w+bb.w);
  *(u16x4*)(zn + (long)row*1024 + c) = pk;
}

// ---------------------------------------------------------------------------
// Masked softmax over a bf16 row of LEN; in-place bf16, 16B/lane loads.
// ---------------------------------------------------------------------------
template<int LEN>
__global__ __launch_bounds__(256)
void softmax16(u16* __restrict__ S, int qmask, int off)
{
  constexpr int PER = LEN/256;           // 32
  __shared__ float sh[4];
  const long row = blockIdx.x;
  const int qi = ((int)row) & qmask;
  const int lim = off + qi;
  u16* srow = S + row*(long)LEN;
  const int tid = threadIdx.x;
  float v[PER];
  float mx = -3.0e38f;
  #pragma unroll
  for (int i=0;i<PER/8;i++){
    int j0 = i*2048 + tid*8;
    u16x8 t = *(const u16x8*)(srow + j0);
    #pragma unroll
    for (int k=0;k<8;k++){
      float val = (j0+k <= lim) ? b2f(t[k]) : -3.0e38f;
      v[i*8+k] = val;
      mx = fmaxf(mx, val);
    }
  }
  float M = block_reduce(mx, 1, sh);
  float s = 0.f;
  #pragma unroll
  for (int i=0;i<PER;i++){ float e = __expf(v[i]-M); v[i]=e; s+=e; }
  float T = block_reduce(s, 0, sh);
  float inv = 1.0f / T;
  #pragma unroll
  for (int i=0;i<PER/8;i++){
    int j0 = i*2048 + tid*8;
    u16x8 pk;
    #pragma unroll
    for (int k=0;k<8;k++) pk[k] = f2b(v[i*8+k]*inv);
    *(u16x8*)(srow + j0) = pk;
  }
}

// ---------------------------------------------------------------------------
__global__ __launch_bounds__(256)
void pack_bias(const float* __restrict__ bq, const float* __restrict__ bk,
               const float* __restrict__ bv, float* __restrict__ qkvb,
               const float* __restrict__ cbk, const float* __restrict__ cbv,
               float* __restrict__ kvb)
{
  const int l = blockIdx.y;
  const int i = blockIdx.x*256 + threadIdx.x;   // 0..3071
  float v;
  if (i < 1024)      v = bq[l*1024 + i];
  else if (i < 2048) v = bk[l*1024 + i - 1024];
  else               v = bv[l*1024 + i - 2048];
  qkvb[l*3072 + i] = v;
  if (l == 0 && i < 2048)
    kvb[i] = (i < 1024) ? cbk[i] : cbv[i - 1024];
}

// ---------------------------------------------------------------------------
__global__ __launch_bounds__(256)
void transpose_w(const float* cwq, const float* cwk, const float* cwv,
                 const float* cwo, const float* cw1, const float* cw2,
                 const float* swq, const float* swk, const float* swv,
                 const float* swo, const float* sw1, const float* sw2,
                 u16* __restrict__ wT)
{
  const int slot = blockIdx.z;
  const float* W;
  switch (slot) {
    case 0:  W = cwq; break;  case 1:  W = cwk; break;
    case 2:  W = cwv; break;  case 3:  W = cwo; break;
    case 4:  W = cw1; break;  case 5:  W = cw2; break;
    case 6:  W = swq; break;  case 7:  W = swk; break;
    case 8:  W = swv; break;  case 9:  W = swo; break;
    case 10: W = sw1; break;  case 11: W = sw2; break;
    case 12: W = swq + 1048576; break; case 13: W = swk + 1048576; break;
    case 14: W = swv + 1048576; break; case 15: W = swo + 1048576; break;
    case 16: W = sw1 + 1048576; break; default: W = sw2 + 1048576; break;
  }
  u16* T = wT + (long)slot*1048576;
  __shared__ float t[32][33];
  const int tx = threadIdx.x & 31, ty = threadIdx.x >> 5;
  const int k0 = blockIdx.x*32, n0 = blockIdx.y*32;
  #pragma unroll
  for (int i=0;i<4;i++)
    t[ty + i*8][tx] = W[(long)(k0 + ty + i*8)*1024 + n0 + tx];
  __syncthreads();
  #pragma unroll
  for (int i=0;i<4;i++)
    T[(long)(n0 + ty + i*8)*1024 + k0 + tx] = f2b(t[tx][ty + i*8]);
}

// ---------------------------------------------------------------------------
extern "C" void kernel_launch(void* const* d_in, const int* in_sizes, int n_in,
                              void* d_out, int out_size, void* d_ws, size_t ws_size,
                              hipStream_t stream)
{
  (void)in_sizes; (void)n_in; (void)out_size;
  const int*   inputs   = (const int*)  d_in[0];
  const float* emb      = (const float*)d_in[1];
  const float* c_lnq_g  = (const float*)d_in[2];
  const float* c_lnq_b  = (const float*)d_in[3];
  const float* c_lnkv_g = (const float*)d_in[4];
  const float* c_lnkv_b = (const float*)d_in[5];
  const float* c_bq = (const float*)d_in[7];
  const float* c_bk = (const float*)d_in[9];
  const float* c_bv = (const float*)d_in[11];
  const float* c_bo = (const float*)d_in[13];
  const float* c_ln2_g = (const float*)d_in[14];
  const float* c_ln2_b = (const float*)d_in[15];
  const float* c_b1 = (const float*)d_in[17];
  const float* c_b2 = (const float*)d_in[19];
  const float* s_lnq_g = (const float*)d_in[20];
  const float* s_lnq_b = (const float*)d_in[21];
  const float* s_bq = (const float*)d_in[23];
  const float* s_bk = (const float*)d_in[25];
  const float* s_bv = (const float*)d_in[27];
  const float* s_bo = (const float*)d_in[29];
  const float* s_ln2_g = (const float*)d_in[30];
  const float* s_ln2_b = (const float*)d_in[31];
  const float* s_b1 = (const float*)d_in[33];
  const float* s_b2 = (const float*)d_in[35];

  const long MB1 = 1048576;
  const long PB  = 8388608;       // P elements per batch (1024 x 8192 u16)

  char* wsb = (char*)d_ws;
  size_t off = 0;
  auto alloc = [&](size_t n)->char* {
    char* p = wsb + off; off += (n + 255) & ~(size_t)255; return p;
  };
  u16*   wT       = (u16*)  alloc((size_t)18*1048576*2);   // 36 MB
  u16*   Ktab     = (u16*)  alloc((size_t)8192*1024*2);    // 16 MB ┐ adjacent
  u16*   Vtab     = (u16*)  alloc((size_t)8192*1024*2);    // 16 MB ┘
  u16*   VTcb     = (u16*)  alloc((size_t)1024*8192*2);    // 16 MB
  u16*   Q        = (u16*)  alloc((size_t)4096*1024*2);    // 8 MB
  u16*   O        = (u16*)  alloc((size_t)4096*1024*2);    // 8 MB
  u16*   Opart16  = (u16*)  alloc((size_t)8*1024*1024*4);  // 32 MB region
  u16*   P4       = (u16*)  alloc((size_t)4*1024*8192*2);  // 64 MB: P (cross)
  // aliases inside P4 (all dead while P is live):
  u16*   lnkv_tab = P4;                                    // 16 MB
  u16*   zn       = P4 +  8*MB1;                           // 8 MB
  u16*   h1       = P4 + 12*MB1;                           // 8 MB
  u16*   Qs       = P4 + 16*MB1;                           // 8 MB
  u16*   Ks       = P4 + 20*MB1;                           // 8 MB
  u16*   VsT      = P4 + 24*MB1;                           // 8 MB
  float* qkvb     = (float*)alloc((size_t)2*3072*4);
  float* kvb      = (float*)alloc((size_t)2048*4);
  float* z        = (float*)d_out;

  if (ws_size < off) return;  // ws too small: leave output zeroed (diagnostic)

  // ---- setup -------------------------------------------------------------
  transpose_w<<<dim3(32,32,18), 256, 0, stream>>>(
      (const float*)d_in[6], (const float*)d_in[8], (const float*)d_in[10],
      (const float*)d_in[12], (const float*)d_in[16], (const float*)d_in[18],
      (const float*)d_in[22], (const float*)d_in[24], (const float*)d_in[26],
      (const float*)d_in[28], (const float*)d_in[32], (const float*)d_in[34], wT);
  pack_bias<<<dim3(12,2), 256, 0, stream>>>(s_bq, s_bk, s_bv, qkvb,
                                            c_bk, c_bv, kvb);
  ln_kernel<0><<<8192, 256, 0, stream>>>(emb, c_lnkv_g, c_lnkv_b,
                                         nullptr, nullptr, lnkv_tab, nullptr);
  zinit_ln<<<4096, 256, 0, stream>>>(inputs, emb, c_lnq_g, c_lnq_b, z, zn);

  // ---- cross attention ---------------------------------------------------
  // K/V vocab tables (z over adjacent wk|wv slots), MT=4 (4/CU)
  gemm_nt<0,false,4,0><<<dim3(64,8,2),256,0,stream>>>(
      lnkv_tab, 0,0,1, 1024,
      wT + 1*MB1, nullptr, 0, MB1,0,1, 1024,
      kvb, 1024,
      Ktab, PB,0,1, 1024, 1024);
  // Q projection, MT=2
  gemm_nt<0,false,2,0><<<dim3(64,8,1),256,0,stream>>>(
      zn, 0,0,1, 1024,
      wT + 0*MB1, nullptr, 0, 0,0,1, 1024,
      c_bq, 0,
      Q, 0,0,1, 1024, 1024);
  // scores for ALL 4 batches (bf16, *1/32), MT=4, SWAP=1 (B-panel L2 reuse:
  // FETCH 70 MB ~= traffic floor, measured rounds 10-13)
  gemm_nt<5,true,4,1><<<dim3(64,8,4),256,0,stream>>>(
      Q, MB1,0,1, 1024,
      Ktab, inputs, 8192, 0,0,1, 1024,
      nullptr, 0,
      P4, PB,0,1, 8192, 1024);
  softmax16<8192><<<4096, 256, 0, stream>>>(P4, 1023, 7168);
  for (int b = 0; b < 4; ++b) {
    gather_T<<<dim3(128,16),256,0,stream>>>(Vtab, inputs + (long)b*8192, VTcb);
    // split-K PV: 8 chunks of K=1024, bf16 partials, 1024 blocks (4/CU)
    gemm_nt<6,false,2,0><<<dim3(16,8,8),256,0,stream>>>(
        P4 + (long)b*PB, 0,1024,8, 8192,
        VTcb, nullptr, 0, 0,1024,8, 8192,
        nullptr, 0,
        Opart16, 1048576,0,1, 1024, 1024);
    reduce8b<<<1024,256,0,stream>>>(Opart16, O + (long)b*MB1);
  }
  // z += O @ wo^T + bo, MT=2
  gemm_nt<2,false,2,0><<<dim3(64,8,1),256,0,stream>>>(
      O, 0,0,1, 1024,
      wT + 3*MB1, nullptr, 0, 0,0,1, 1024,
      c_bo, 0,
      z, 0,0,1, 1024, 1024);

  // ---- central FFN (MT=2) ------------------------------------------------
  ln_kernel<0><<<4096,256,0,stream>>>(z, c_ln2_g, c_ln2_b, nullptr,nullptr, zn, nullptr);
  gemm_nt<1,false,2,0><<<dim3(64,8,1),256,0,stream>>>(
      zn, 0,0,1, 1024,
      wT + 4*MB1, nullptr, 0, 0,0,1, 1024,
      c_b1, 0,
      h1, 0,0,1, 1024, 1024);
  gemm_nt<2,false,2,0><<<dim3(64,8,1),256,0,stream>>>(
      h1, 0,0,1, 1024,
      wT + 5*MB1, nullptr, 0, 0,0,1, 1024,
      c_b2, 0,
      z, 0,0,1, 1024, 1024);

  // ---- self-attention blocks (NB*L = 4, l = 0,1,0,1) ---------------------
  for (int it = 0; it < 4; ++it) {
    const int l = it & 1;
    const u16* wqkv = wT + (size_t)(6 + l*6)*MB1;
    const u16* wo = wT + (size_t)(6 + l*6 + 3)*MB1;
    const u16* w1 = wT + (size_t)(6 + l*6 + 4)*MB1;
    const u16* w2 = wT + (size_t)(6 + l*6 + 5)*MB1;

    ln_kernel<0><<<4096,256,0,stream>>>(z, s_lnq_g + l*1024, s_lnq_b + l*1024,
                                        nullptr,nullptr, zn, nullptr);
    gemm_qkv<<<dim3(64,24),256,0,stream>>>(zn, wqkv, qkvb + l*3072, Qs, Ks, VsT);
    flash_self<<<dim3(32,16),256,0,stream>>>(Qs, Ks, VsT, O);
    gemm_nt<2,false,2,0><<<dim3(64,8,1),256,0,stream>>>(
        O, 0,0,1, 1024,  wo, nullptr, 0, 0,0,1, 1024,
        s_bo + l*1024, 0,
        z, 0,0,1, 1024, 1024);

    ln_kernel<0><<<4096,256,0,stream>>>(z, s_ln2_g + l*1024, s_ln2_b + l*1024,
                                        nullptr,nullptr, zn, nullptr);
    gemm_nt<1,false,2,0><<<dim3(64,8,1),256,0,stream>>>(
        zn, 0,0,1, 1024,  w1, nullptr, 0, 0,0,1, 1024,
        s_b1 + l*1024, 0,
        h1, 0,0,1, 1024, 1024);
    gemm_nt<2,false,2,0><<<dim3(64,8,1),256,0,stream>>>(
        h1, 0,0,1, 1024,  w2, nullptr, 0, 0,0,1, 1024,
        s_b2 + l*1024, 0,
        z, 0,0,1, 1024, 1024);
  }
}